// Round 9
// baseline (603.726 us; speedup 1.0000x reference)
//
#include <hip/hip_runtime.h>
#include <math.h>

typedef _Float16 half8_t __attribute__((ext_vector_type(8)));
typedef _Float16 half4_t __attribute__((ext_vector_type(4)));
typedef float    f32x4_t __attribute__((ext_vector_type(4)));

// ---------------- CSR build ----------------

__global__ __launch_bounds__(256) void hist_k(const int* __restrict__ dst, int* __restrict__ cnt,
                                              unsigned short* __restrict__ rank, int E){
  int e = blockIdx.x*256 + threadIdx.x;
  if (e < E) rank[e] = (unsigned short)atomicAdd(&cnt[dst[e]], 1);
}

__global__ __launch_bounds__(256) void blocksum_k(const int* __restrict__ cnt, int* __restrict__ bsum, int N){
  int i = blockIdx.x*256 + threadIdx.x;
  int v = (i < N) ? cnt[i] : 0;
  #pragma unroll
  for (int off = 32; off; off >>= 1) v += __shfl_down(v, off, 64);
  __shared__ int s[4];
  if ((threadIdx.x & 63) == 0) s[threadIdx.x >> 6] = v;
  __syncthreads();
  if (threadIdx.x == 0) bsum[blockIdx.x] = s[0] + s[1] + s[2] + s[3];
}

__global__ __launch_bounds__(512) void scan_small_k(const int* __restrict__ bsum, int* __restrict__ boff, int NB){
  __shared__ int s[512];
  int t = threadIdx.x;
  int v = (t < NB) ? bsum[t] : 0;
  s[t] = v; __syncthreads();
  for (int off = 1; off < 512; off <<= 1){
    int x = (t >= off) ? s[t-off] : 0;
    __syncthreads();
    s[t] += x;
    __syncthreads();
  }
  if (t < NB) boff[t] = s[t] - v;
}

__global__ __launch_bounds__(256) void scan_final_k(const int* __restrict__ cnt, const int* __restrict__ boff,
                                                    int* __restrict__ rowptr,
                                                    float* __restrict__ dinv, int N){
  __shared__ int s[256];
  int t = threadIdx.x;
  int i = blockIdx.x*256 + t;
  int v = (i < N) ? cnt[i] : 0;
  s[t] = v; __syncthreads();
  for (int off = 1; off < 256; off <<= 1){
    int x = (t >= off) ? s[t-off] : 0;
    __syncthreads();
    s[t] += x;
    __syncthreads();
  }
  int excl = s[t] - v + boff[blockIdx.x];
  if (i < N){
    rowptr[i] = excl;
    dinv[i]   = rsqrtf((float)v + 1.0f);
    if (i == N-1) rowptr[N] = excl + v;
  }
}

// pure scatter, 2 edges per thread, no atomic dependency
__global__ __launch_bounds__(256) void fill_k(const int* __restrict__ src, const int* __restrict__ dst,
                                              const int* __restrict__ rowptr,
                                              const unsigned short* __restrict__ rank,
                                              int* __restrict__ col, int E){
  int e2 = (blockIdx.x*256 + threadIdx.x) * 2;
  if (e2 >= E) return;
  int2 d = *(const int2*)&dst[e2];
  int2 s = *(const int2*)&src[e2];
  ushort2 r = *(const ushort2*)&rank[e2];
  col[rowptr[d.x] + r.x] = s.x;
  col[rowptr[d.y] + r.y] = s.y;
}

// ---------------- weight prep: Bt[m][n][k] = (fp16) W_m[k][n] ----------------

__global__ __launch_bounds__(256) void prepw_k(const float* __restrict__ Win, const float* __restrict__ Wgnn,
                                               _Float16* __restrict__ Bt){
  int idx = blockIdx.x*256 + threadIdx.x;     // 4*16384 total
  int m = idx >> 14;
  int r = idx & 16383;
  int k = r >> 7, n = r & 127;
  const float* W = (m == 0) ? Win : (Wgnn + (size_t)(m-1)*16384);
  Bt[(size_t)m*16384 + n*128 + k] = (_Float16)W[k*128 + n];
}

// ---------------- MFMA fp16 GEMM: M x 128 x 128 ----------------
// EPI 0: C = (fp16) relu(A@W + bias); EPI 1: C = (fp16) dinv[row]*(A@W)

template<int AF16, int EPI>
__global__ __launch_bounds__(256) void mgemm_k(const void* __restrict__ Ap, const _Float16* __restrict__ Bt,
                                               const float* __restrict__ bias, const float* __restrict__ dinv,
                                               _Float16* __restrict__ C, int M){
  __shared__ _Float16 As[128*128];
  __shared__ _Float16 Bs[128*128];
  const int tid = threadIdx.x;
  const int m0 = blockIdx.x * 128;

  {
    int n = tid >> 1, kb = (tid & 1) * 64;
    const half8_t* srcb = (const half8_t*)(Bt + n*128 + kb);
    #pragma unroll
    for (int q = 0; q < 8; ++q){
      uint32_t byte = (uint32_t)(n*256 + kb*2 + q*16) ^ (uint32_t)((n & 7) << 4);
      *(half8_t*)((char*)Bs + byte) = srcb[q];
    }
  }
  {
    int rr = tid >> 1, kb = (tid & 1) * 64;
    int row = m0 + rr; if (row >= M) row = M - 1;
    if (AF16){
      const half8_t* srca = (const half8_t*)((const _Float16*)Ap + (size_t)row*128 + kb);
      #pragma unroll
      for (int q = 0; q < 8; ++q){
        uint32_t byte = (uint32_t)(rr*256 + kb*2 + q*16) ^ (uint32_t)((rr & 7) << 4);
        *(half8_t*)((char*)As + byte) = srca[q];
      }
    } else {
      const float4* srca = (const float4*)((const float*)Ap + (size_t)row*128 + kb);
      #pragma unroll
      for (int q = 0; q < 8; ++q){
        float4 f0 = srca[2*q], f1 = srca[2*q+1];
        half8_t h;
        h[0]=(_Float16)f0.x; h[1]=(_Float16)f0.y; h[2]=(_Float16)f0.z; h[3]=(_Float16)f0.w;
        h[4]=(_Float16)f1.x; h[5]=(_Float16)f1.y; h[6]=(_Float16)f1.z; h[7]=(_Float16)f1.w;
        uint32_t byte = (uint32_t)(rr*256 + kb*2 + q*16) ^ (uint32_t)((rr & 7) << 4);
        *(half8_t*)((char*)As + byte) = h;
      }
    }
  }
  __syncthreads();

  const int w = tid >> 6, lane = tid & 63;
  const int l15 = lane & 15, lq = lane >> 4;

  f32x4_t acc[2][8];
  #pragma unroll
  for (int rg = 0; rg < 2; ++rg)
    #pragma unroll
    for (int cg = 0; cg < 8; ++cg)
      acc[rg][cg] = (f32x4_t){0.f,0.f,0.f,0.f};

  #pragma unroll
  for (int ks = 0; ks < 4; ++ks){
    half8_t a[2], b[8];
    #pragma unroll
    for (int rg = 0; rg < 2; ++rg){
      int row = w*32 + rg*16 + l15;
      uint32_t byte = (uint32_t)(row*256 + (ks*32 + lq*8)*2) ^ (uint32_t)((row & 7) << 4);
      a[rg] = *(const half8_t*)((const char*)As + byte);
    }
    #pragma unroll
    for (int cg = 0; cg < 8; ++cg){
      int coln = cg*16 + l15;
      uint32_t byte = (uint32_t)(coln*256 + (ks*32 + lq*8)*2) ^ (uint32_t)((coln & 7) << 4);
      b[cg] = *(const half8_t*)((const char*)Bs + byte);
    }
    #pragma unroll
    for (int rg = 0; rg < 2; ++rg)
      #pragma unroll
      for (int cg = 0; cg < 8; ++cg)
        acc[rg][cg] = __builtin_amdgcn_mfma_f32_16x16x32_f16(a[rg], b[cg], acc[rg][cg], 0, 0, 0);
  }

  float bl[8];
  if (EPI == 0){
    #pragma unroll
    for (int cg = 0; cg < 8; ++cg) bl[cg] = bias[cg*16 + l15];
  }

  #pragma unroll
  for (int rg = 0; rg < 2; ++rg){
    #pragma unroll
    for (int r = 0; r < 4; ++r){
      int grow = m0 + w*32 + rg*16 + lq*4 + r;
      if (grow < M){
        if (EPI == 1){
          float di = dinv[grow];
          #pragma unroll
          for (int cg = 0; cg < 8; ++cg)
            C[(size_t)grow*128 + cg*16 + l15] = (_Float16)(di * acc[rg][cg][r]);
        } else {
          #pragma unroll
          for (int cg = 0; cg < 8; ++cg){
            float v = acc[rg][cg][r] + bl[cg];
            C[(size_t)grow*128 + cg*16 + l15] = (_Float16)fmaxf(v, 0.f);
          }
        }
      }
    }
  }
}

// ---------------- GEMM 64x64 fp32 (small head GEMMs) ----------------

template<int ACT>
__global__ __launch_bounds__(256) void gemm_k(const float* __restrict__ A, const float* __restrict__ B,
                                              const float* __restrict__ bias, float* __restrict__ C,
                                              int M, int N, int K){
  __shared__ float As[16][68];
  __shared__ float Bs[16][68];
  int tid = threadIdx.x;
  int m0 = blockIdx.x * 64, n0 = blockIdx.y * 64;
  int ty = tid >> 4, tx = tid & 15;
  int lm = tid >> 2, lkq = tid & 3;
  int lk = tid >> 4, ln4 = tid & 15;
  int arow = m0 + lm; if (arow >= M) arow = M - 1;

  float acc[4][4] = {{0.f}};

  for (int k0 = 0; k0 < K; k0 += 16){
    float4 av = *(const float4*)&A[(size_t)arow*K + k0 + lkq*4];
    float4 bv = *(const float4*)&B[(size_t)(k0+lk)*N + n0 + ln4*4];
    As[lkq*4+0][lm] = av.x; As[lkq*4+1][lm] = av.y; As[lkq*4+2][lm] = av.z; As[lkq*4+3][lm] = av.w;
    *(float4*)&Bs[lk][ln4*4] = bv;
    __syncthreads();
    #pragma unroll
    for (int kk = 0; kk < 16; ++kk){
      const float4 a = *(const float4*)&As[kk][ty*4];
      const float4 b = *(const float4*)&Bs[kk][tx*4];
      acc[0][0] += a.x*b.x; acc[0][1] += a.x*b.y; acc[0][2] += a.x*b.z; acc[0][3] += a.x*b.w;
      acc[1][0] += a.y*b.x; acc[1][1] += a.y*b.y; acc[1][2] += a.y*b.z; acc[1][3] += a.y*b.w;
      acc[2][0] += a.z*b.x; acc[2][1] += a.z*b.y; acc[2][2] += a.z*b.z; acc[2][3] += a.z*b.w;
      acc[3][0] += a.w*b.x; acc[3][1] += a.w*b.y; acc[3][2] += a.w*b.z; acc[3][3] += a.w*b.w;
    }
    __syncthreads();
  }

  float bv0 = 0.f, bv1 = 0.f, bv2 = 0.f, bv3 = 0.f;
  if (bias){
    const float4 b4 = *(const float4*)&bias[n0 + tx*4];
    bv0 = b4.x; bv1 = b4.y; bv2 = b4.z; bv3 = b4.w;
  }
  #pragma unroll
  for (int i = 0; i < 4; ++i){
    int r = m0 + ty*4 + i;
    if (r < M){
      float4 o;
      o.x = acc[i][0] + bv0; o.y = acc[i][1] + bv1; o.z = acc[i][2] + bv2; o.w = acc[i][3] + bv3;
      if (ACT == 1){ o.x = fmaxf(o.x,0.f); o.y = fmaxf(o.y,0.f); o.z = fmaxf(o.z,0.f); o.w = fmaxf(o.w,0.f); }
      *(float4*)&C[(size_t)r*N + n0 + tx*4] = o;
    }
  }
}

// ---------------- GCN aggregation + BN + ReLU ----------------
// 16 independent row-loads in flight per wave (2 halves x unroll 8).

__global__ __launch_bounds__(256) void agg_k(const _Float16* __restrict__ hws, _Float16* __restrict__ hout,
                                             const int* __restrict__ rowptr, const int* __restrict__ col,
                                             const float* __restrict__ dinv,
                                             const float* __restrict__ bgnn, const float* __restrict__ gamma,
                                             const float* __restrict__ beta, const float* __restrict__ mean,
                                             const float* __restrict__ var, int N){
  int n = (blockIdx.x * blockDim.x + threadIdx.x) >> 6;
  if (n >= N) return;
  int lane = threadIdx.x & 63;
  int half = lane >> 5;
  int sl   = lane & 31;
  int f    = sl * 4;
  int beg = rowptr[n], end = rowptr[n+1];
  const _Float16* hwsf = hws + f;

  half4_t H0 = {0,0,0,0}, H1 = {0,0,0,0}, H2 = {0,0,0,0}, H3 = {0,0,0,0};
  half4_t H4 = {0,0,0,0}, H5 = {0,0,0,0}, H6 = {0,0,0,0}, H7 = {0,0,0,0};

  int j = beg + half;
  for (; j + 14 < end; j += 16){
    int s0 = col[j],    s1 = col[j+2],  s2 = col[j+4],  s3 = col[j+6];
    int s4 = col[j+8],  s5 = col[j+10], s6 = col[j+12], s7 = col[j+14];
    H0 += *(const half4_t*)&hwsf[(size_t)s0*128];
    H1 += *(const half4_t*)&hwsf[(size_t)s1*128];
    H2 += *(const half4_t*)&hwsf[(size_t)s2*128];
    H3 += *(const half4_t*)&hwsf[(size_t)s3*128];
    H4 += *(const half4_t*)&hwsf[(size_t)s4*128];
    H5 += *(const half4_t*)&hwsf[(size_t)s5*128];
    H6 += *(const half4_t*)&hwsf[(size_t)s6*128];
    H7 += *(const half4_t*)&hwsf[(size_t)s7*128];
  }
  for (; j + 6 < end; j += 8){
    int s0 = col[j], s1 = col[j+2], s2 = col[j+4], s3 = col[j+6];
    H0 += *(const half4_t*)&hwsf[(size_t)s0*128];
    H1 += *(const half4_t*)&hwsf[(size_t)s1*128];
    H2 += *(const half4_t*)&hwsf[(size_t)s2*128];
    H3 += *(const half4_t*)&hwsf[(size_t)s3*128];
  }
  for (; j < end; j += 2){
    int s0 = col[j];
    H0 += *(const half4_t*)&hwsf[(size_t)s0*128];
  }

  float4 A0;
  A0.x = ((float)H0[0] + (float)H1[0]) + ((float)H2[0] + (float)H3[0])
       + ((float)H4[0] + (float)H5[0]) + ((float)H6[0] + (float)H7[0]);
  A0.y = ((float)H0[1] + (float)H1[1]) + ((float)H2[1] + (float)H3[1])
       + ((float)H4[1] + (float)H5[1]) + ((float)H6[1] + (float)H7[1]);
  A0.z = ((float)H0[2] + (float)H1[2]) + ((float)H2[2] + (float)H3[2])
       + ((float)H4[2] + (float)H5[2]) + ((float)H6[2] + (float)H7[2]);
  A0.w = ((float)H0[3] + (float)H1[3]) + ((float)H2[3] + (float)H3[3])
       + ((float)H4[3] + (float)H5[3]) + ((float)H6[3] + (float)H7[3]);

  A0.x += __shfl_xor(A0.x, 32, 64);
  A0.y += __shfl_xor(A0.y, 32, 64);
  A0.z += __shfl_xor(A0.z, 32, 64);
  A0.w += __shfl_xor(A0.w, 32, 64);

  if (half == 0){
    float di = dinv[n];
    const half4_t hv = *(const half4_t*)&hwsf[(size_t)n*128];
    const float4 bg = *(const float4*)&bgnn[f];
    const float4 gm = *(const float4*)&gamma[f];
    const float4 bt = *(const float4*)&beta[f];
    const float4 mn = *(const float4*)&mean[f];
    const float4 vr = *(const float4*)&var[f];
    float o0 = (di*(A0.x + (float)hv[0]) + bg.x - mn.x) * (gm.x * rsqrtf(vr.x + 1e-5f)) + bt.x;
    float o1 = (di*(A0.y + (float)hv[1]) + bg.y - mn.y) * (gm.y * rsqrtf(vr.y + 1e-5f)) + bt.y;
    float o2 = (di*(A0.z + (float)hv[2]) + bg.z - mn.z) * (gm.z * rsqrtf(vr.z + 1e-5f)) + bt.z;
    float o3 = (di*(A0.w + (float)hv[3]) + bg.w - mn.w) * (gm.w * rsqrtf(vr.w + 1e-5f)) + bt.w;
    half4_t o;
    o[0] = (_Float16)fmaxf(o0, 0.f);
    o[1] = (_Float16)fmaxf(o1, 0.f);
    o[2] = (_Float16)fmaxf(o2, 0.f);
    o[3] = (_Float16)fmaxf(o3, 0.f);
    *(half4_t*)&hout[(size_t)n*128 + f] = o;
  }
}

// ---------------- user gather, nlp bias (fused), head ----------------

__global__ __launch_bounds__(256) void gather_k(const _Float16* __restrict__ h, const int* __restrict__ uidx,
                                                float* __restrict__ uh, int B){
  int g = blockIdx.x*256 + threadIdx.x;
  if (g >= B*128) return;
  int i = g >> 7, f = g & 127;
  uh[g] = (float)h[(size_t)uidx[i]*128 + f];
}

// c1[c] = b1[c] + sum_d nlp[d]*W1[64+d][c]; grid 4 blocks x 64 cols, no atomics
__global__ __launch_bounds__(256) void c1_k(const float* __restrict__ nlp, const float* __restrict__ W1,
                                            const float* __restrict__ b1, float* __restrict__ c1, int NLP){
  int c  = blockIdx.x * 64 + (threadIdx.x & 63);
  int dq = threadIdx.x >> 6;
  float acc = 0.f;
  for (int d = dq; d < NLP; d += 4)
    acc += nlp[d] * W1[(size_t)(64 + d) * 256 + c];
  __shared__ float s[256];
  s[threadIdx.x] = acc; __syncthreads();
  if (dq == 0)
    c1[c] = b1[c] + s[threadIdx.x] + s[threadIdx.x + 64] + s[threadIdx.x + 128] + s[threadIdx.x + 192];
}

__global__ __launch_bounds__(256) void head_k(const float* __restrict__ z2, const float* __restrict__ W3,
                                              const float* __restrict__ b3, float* __restrict__ out, int B){
  int gid = blockIdx.x * blockDim.x + threadIdx.x;
  int u = gid >> 6, l = gid & 63;
  if (u >= B) return;
  float v = z2[(size_t)u*128 + l] * W3[l] + z2[(size_t)u*128 + 64 + l] * W3[64 + l];
  #pragma unroll
  for (int off = 32; off; off >>= 1) v += __shfl_down(v, off, 64);
  if (l == 0) out[u] = 1.f / (1.f + expf(-(v + b3[0])));
}

// ---------------- host ----------------

static void launch_gemm(int act, const float* A, const float* Bm, const float* bias, float* C,
                        int M, int N, int K, hipStream_t s){
  dim3 g((M + 63) / 64, N / 64);
  if (act) hipLaunchKernelGGL((gemm_k<1>), g, dim3(256), 0, s, A, Bm, bias, C, M, N, K);
  else     hipLaunchKernelGGL((gemm_k<0>), g, dim3(256), 0, s, A, Bm, bias, C, M, N, K);
}

extern "C" void kernel_launch(void* const* d_in, const int* in_sizes, int n_in,
                              void* d_out, int out_size, void* d_ws, size_t ws_size,
                              hipStream_t stream){
  const float* x     = (const float*)d_in[0];
  const float* nlp   = (const float*)d_in[1];
  const int*   eidx  = (const int*)  d_in[2];
  const int*   uidx  = (const int*)  d_in[3];
  const float* W_in  = (const float*)d_in[4];
  const float* b_in  = (const float*)d_in[5];
  const float* W_gnn = (const float*)d_in[6];
  const float* b_gnn = (const float*)d_in[7];
  const float* gam   = (const float*)d_in[8];
  const float* bet   = (const float*)d_in[9];
  const float* mean  = (const float*)d_in[10];
  const float* var   = (const float*)d_in[11];
  const float* Wproj = (const float*)d_in[12];
  const float* bproj = (const float*)d_in[13];
  const float* W1    = (const float*)d_in[14];
  const float* b1    = (const float*)d_in[15];
  const float* W2    = (const float*)d_in[16];
  const float* b2    = (const float*)d_in[17];
  const float* W3    = (const float*)d_in[18];
  const float* b3    = (const float*)d_in[19];
  float* out = (float*)d_out;

  const int N   = in_sizes[0] / 128;   // 100000
  const int E   = in_sizes[2] / 2;     // 1600000
  const int B   = in_sizes[3];         // 4096
  const int NLP = in_sizes[1];         // 786
  const int HID = 128;

  char* p = (char*)d_ws;
  auto carve = [&](size_t bytes) -> void* {
    void* q = (void*)p;
    p += (bytes + 255) & ~(size_t)255;
    return q;
  };
  int*            cnt    = (int*)           carve((size_t)N * 4);
  int*            rowptr = (int*)           carve((size_t)(N + 1) * 4);
  unsigned short* rank   = (unsigned short*)carve((size_t)E * 2);
  int*            bsum   = (int*)           carve(512 * 4);
  int*            boff   = (int*)           carve(512 * 4);
  float*          dinv   = (float*)         carve((size_t)N * 4);
  int*            col    = (int*)           carve((size_t)E * 4);
  _Float16*       Bt     = (_Float16*)      carve((size_t)4 * 128 * 128 * 2);
  _Float16*       h      = (_Float16*)      carve((size_t)N * HID * 2);
  _Float16*       hws    = (_Float16*)      carve((size_t)N * HID * 2);
  float*          uh     = (float*)         carve((size_t)B * HID * 4);
  float*          embu   = (float*)         carve((size_t)B * 64 * 4);
  float*          z1     = (float*)         carve((size_t)B * 256 * 4);
  float*          z2     = (float*)         carve((size_t)B * 128 * 4);
  float*          c1     = (float*)         carve(256 * 4);

  const int* src = eidx;
  const int* dst = eidx + E;

  const int NB = (N + 255) / 256;   // 391 (<512)
  const int GB = (N + 127) / 128;   // 782 gemm blocks

  // ---- CSR build ----
  hipMemsetAsync(cnt, 0, (size_t)N * 4, stream);
  hipLaunchKernelGGL(hist_k, dim3((E + 255) / 256), dim3(256), 0, stream, dst, cnt, rank, E);
  hipLaunchKernelGGL(blocksum_k, dim3(NB), dim3(256), 0, stream, cnt, bsum, N);
  hipLaunchKernelGGL(scan_small_k, dim3(1), dim3(512), 0, stream, bsum, boff, NB);
  hipLaunchKernelGGL(scan_final_k, dim3(NB), dim3(256), 0, stream, cnt, boff, rowptr, dinv, N);
  hipLaunchKernelGGL(fill_k, dim3((E/2 + 255) / 256), dim3(256), 0, stream, src, dst, rowptr, rank, col, E);

  // ---- weight prep (fp16, transposed) ----
  hipLaunchKernelGGL(prepw_k, dim3(256), dim3(256), 0, stream, W_in, W_gnn, Bt);

  // ---- input projection: h = (fp16) relu(x @ W_in + b_in)  [MFMA] ----
  hipLaunchKernelGGL((mgemm_k<0,0>), dim3(GB), dim3(256), 0, stream,
                     (const void*)x, Bt, b_in, (const float*)nullptr, h, N);

  // ---- 3 GCN layers ----
  for (int i = 0; i < 3; ++i){
    hipLaunchKernelGGL((mgemm_k<1,1>), dim3(GB), dim3(256), 0, stream,
                       (const void*)h, Bt + (size_t)(i+1)*16384, (const float*)nullptr, dinv, hws, N);
    hipLaunchKernelGGL(agg_k, dim3((N * 64 + 255) / 256), dim3(256), 0, stream,
                       hws, h, rowptr, col, dinv,
                       b_gnn + i * 128, gam + i * 128, bet + i * 128, mean + i * 128, var + i * 128, N);
  }

  // ---- user head ----
  hipLaunchKernelGGL(gather_k, dim3((B * 128 + 255) / 256), dim3(256), 0, stream, h, uidx, uh, B);
  hipLaunchKernelGGL(c1_k, dim3(4), dim3(256), 0, stream, nlp, W1, b1, c1, NLP);

  launch_gemm(0, uh, Wproj, bproj, embu, B, 64, 128, stream);
  launch_gemm(1, embu, W1, c1, z1, B, 256, 64, stream);
  launch_gemm(1, z1, W2, b2, z2, B, 128, 256, stream);
  hipLaunchKernelGGL(head_k, dim3((B * 64 + 255) / 256), dim3(256), 0, stream, z2, W3, b3, out, B);
}

// Round 10
// 559.524 us; speedup vs baseline: 1.0790x; 1.0790x over previous
//
#include <hip/hip_runtime.h>
#include <math.h>

typedef _Float16 half8_t __attribute__((ext_vector_type(8)));
typedef _Float16 half4_t __attribute__((ext_vector_type(4)));
typedef float    f32x4_t __attribute__((ext_vector_type(4)));

// ---------------- CSR build ----------------

__global__ __launch_bounds__(256) void hist_k(const int* __restrict__ dst, int* __restrict__ cnt,
                                              unsigned short* __restrict__ rank, int E){
  int e = blockIdx.x*256 + threadIdx.x;
  if (e < E) rank[e] = (unsigned short)atomicAdd(&cnt[dst[e]], 1);
}

__global__ __launch_bounds__(256) void blocksum_k(const int* __restrict__ cnt, int* __restrict__ bsum, int N){
  int i = blockIdx.x*256 + threadIdx.x;
  int v = (i < N) ? cnt[i] : 0;
  #pragma unroll
  for (int off = 32; off; off >>= 1) v += __shfl_down(v, off, 64);
  __shared__ int s[4];
  if ((threadIdx.x & 63) == 0) s[threadIdx.x >> 6] = v;
  __syncthreads();
  if (threadIdx.x == 0) bsum[blockIdx.x] = s[0] + s[1] + s[2] + s[3];
}

__global__ __launch_bounds__(512) void scan_small_k(const int* __restrict__ bsum, int* __restrict__ boff, int NB){
  __shared__ int s[512];
  int t = threadIdx.x;
  int v = (t < NB) ? bsum[t] : 0;
  s[t] = v; __syncthreads();
  for (int off = 1; off < 512; off <<= 1){
    int x = (t >= off) ? s[t-off] : 0;
    __syncthreads();
    s[t] += x;
    __syncthreads();
  }
  if (t < NB) boff[t] = s[t] - v;
}

__global__ __launch_bounds__(256) void scan_final_k(const int* __restrict__ cnt, const int* __restrict__ boff,
                                                    int* __restrict__ rowptr,
                                                    float* __restrict__ dinv, int N){
  __shared__ int s[256];
  int t = threadIdx.x;
  int i = blockIdx.x*256 + t;
  int v = (i < N) ? cnt[i] : 0;
  s[t] = v; __syncthreads();
  for (int off = 1; off < 256; off <<= 1){
    int x = (t >= off) ? s[t-off] : 0;
    __syncthreads();
    s[t] += x;
    __syncthreads();
  }
  int excl = s[t] - v + boff[blockIdx.x];
  if (i < N){
    rowptr[i] = excl;
    dinv[i]   = rsqrtf((float)v + 1.0f);
    if (i == N-1) rowptr[N] = excl + v;
  }
}

// pure scatter, 2 edges per thread, no atomic dependency
__global__ __launch_bounds__(256) void fill_k(const int* __restrict__ src, const int* __restrict__ dst,
                                              const int* __restrict__ rowptr,
                                              const unsigned short* __restrict__ rank,
                                              int* __restrict__ col, int E){
  int e2 = (blockIdx.x*256 + threadIdx.x) * 2;
  if (e2 >= E) return;
  int2 d = *(const int2*)&dst[e2];
  int2 s = *(const int2*)&src[e2];
  ushort2 r = *(const ushort2*)&rank[e2];
  col[rowptr[d.x] + r.x] = s.x;
  col[rowptr[d.y] + r.y] = s.y;
}

// ---------------- weight prep: Bt[m][n][k] = (fp16) W_m[k][n] ----------------

__global__ __launch_bounds__(256) void prepw_k(const float* __restrict__ Win, const float* __restrict__ Wgnn,
                                               _Float16* __restrict__ Bt){
  int idx = blockIdx.x*256 + threadIdx.x;     // 4*16384 total
  int m = idx >> 14;
  int r = idx & 16383;
  int k = r >> 7, n = r & 127;
  const float* W = (m == 0) ? Win : (Wgnn + (size_t)(m-1)*16384);
  Bt[(size_t)m*16384 + n*128 + k] = (_Float16)W[k*128 + n];
}

// ---------------- MFMA fp16 GEMM: M x 128 x 128 ----------------
// EPI 0: C = (fp16) relu(A@W + bias); EPI 1: C = (fp16) dinv[row]*(A@W)

template<int AF16, int EPI>
__global__ __launch_bounds__(256) void mgemm_k(const void* __restrict__ Ap, const _Float16* __restrict__ Bt,
                                               const float* __restrict__ bias, const float* __restrict__ dinv,
                                               _Float16* __restrict__ C, int M){
  __shared__ _Float16 As[128*128];
  __shared__ _Float16 Bs[128*128];
  const int tid = threadIdx.x;
  const int m0 = blockIdx.x * 128;

  {
    int n = tid >> 1, kb = (tid & 1) * 64;
    const half8_t* srcb = (const half8_t*)(Bt + n*128 + kb);
    #pragma unroll
    for (int q = 0; q < 8; ++q){
      uint32_t byte = (uint32_t)(n*256 + kb*2 + q*16) ^ (uint32_t)((n & 7) << 4);
      *(half8_t*)((char*)Bs + byte) = srcb[q];
    }
  }
  {
    int rr = tid >> 1, kb = (tid & 1) * 64;
    int row = m0 + rr; if (row >= M) row = M - 1;
    if (AF16){
      const half8_t* srca = (const half8_t*)((const _Float16*)Ap + (size_t)row*128 + kb);
      #pragma unroll
      for (int q = 0; q < 8; ++q){
        uint32_t byte = (uint32_t)(rr*256 + kb*2 + q*16) ^ (uint32_t)((rr & 7) << 4);
        *(half8_t*)((char*)As + byte) = srca[q];
      }
    } else {
      const float4* srca = (const float4*)((const float*)Ap + (size_t)row*128 + kb);
      #pragma unroll
      for (int q = 0; q < 8; ++q){
        float4 f0 = srca[2*q], f1 = srca[2*q+1];
        half8_t h;
        h[0]=(_Float16)f0.x; h[1]=(_Float16)f0.y; h[2]=(_Float16)f0.z; h[3]=(_Float16)f0.w;
        h[4]=(_Float16)f1.x; h[5]=(_Float16)f1.y; h[6]=(_Float16)f1.z; h[7]=(_Float16)f1.w;
        uint32_t byte = (uint32_t)(rr*256 + kb*2 + q*16) ^ (uint32_t)((rr & 7) << 4);
        *(half8_t*)((char*)As + byte) = h;
      }
    }
  }
  __syncthreads();

  const int w = tid >> 6, lane = tid & 63;
  const int l15 = lane & 15, lq = lane >> 4;

  f32x4_t acc[2][8];
  #pragma unroll
  for (int rg = 0; rg < 2; ++rg)
    #pragma unroll
    for (int cg = 0; cg < 8; ++cg)
      acc[rg][cg] = (f32x4_t){0.f,0.f,0.f,0.f};

  #pragma unroll
  for (int ks = 0; ks < 4; ++ks){
    half8_t a[2], b[8];
    #pragma unroll
    for (int rg = 0; rg < 2; ++rg){
      int row = w*32 + rg*16 + l15;
      uint32_t byte = (uint32_t)(row*256 + (ks*32 + lq*8)*2) ^ (uint32_t)((row & 7) << 4);
      a[rg] = *(const half8_t*)((const char*)As + byte);
    }
    #pragma unroll
    for (int cg = 0; cg < 8; ++cg){
      int coln = cg*16 + l15;
      uint32_t byte = (uint32_t)(coln*256 + (ks*32 + lq*8)*2) ^ (uint32_t)((coln & 7) << 4);
      b[cg] = *(const half8_t*)((const char*)Bs + byte);
    }
    #pragma unroll
    for (int rg = 0; rg < 2; ++rg)
      #pragma unroll
      for (int cg = 0; cg < 8; ++cg)
        acc[rg][cg] = __builtin_amdgcn_mfma_f32_16x16x32_f16(a[rg], b[cg], acc[rg][cg], 0, 0, 0);
  }

  float bl[8];
  if (EPI == 0){
    #pragma unroll
    for (int cg = 0; cg < 8; ++cg) bl[cg] = bias[cg*16 + l15];
  }

  #pragma unroll
  for (int rg = 0; rg < 2; ++rg){
    #pragma unroll
    for (int r = 0; r < 4; ++r){
      int grow = m0 + w*32 + rg*16 + lq*4 + r;
      if (grow < M){
        if (EPI == 1){
          float di = dinv[grow];
          #pragma unroll
          for (int cg = 0; cg < 8; ++cg)
            C[(size_t)grow*128 + cg*16 + l15] = (_Float16)(di * acc[rg][cg][r]);
        } else {
          #pragma unroll
          for (int cg = 0; cg < 8; ++cg){
            float v = acc[rg][cg][r] + bl[cg];
            C[(size_t)grow*128 + cg*16 + l15] = (_Float16)fmaxf(v, 0.f);
          }
        }
      }
    }
  }
}

// ---------------- GEMM 64x64 fp32 (small head GEMMs) ----------------

template<int ACT>
__global__ __launch_bounds__(256) void gemm_k(const float* __restrict__ A, const float* __restrict__ B,
                                              const float* __restrict__ bias, float* __restrict__ C,
                                              int M, int N, int K){
  __shared__ float As[16][68];
  __shared__ float Bs[16][68];
  int tid = threadIdx.x;
  int m0 = blockIdx.x * 64, n0 = blockIdx.y * 64;
  int ty = tid >> 4, tx = tid & 15;
  int lm = tid >> 2, lkq = tid & 3;
  int lk = tid >> 4, ln4 = tid & 15;
  int arow = m0 + lm; if (arow >= M) arow = M - 1;

  float acc[4][4] = {{0.f}};

  for (int k0 = 0; k0 < K; k0 += 16){
    float4 av = *(const float4*)&A[(size_t)arow*K + k0 + lkq*4];
    float4 bv = *(const float4*)&B[(size_t)(k0+lk)*N + n0 + ln4*4];
    As[lkq*4+0][lm] = av.x; As[lkq*4+1][lm] = av.y; As[lkq*4+2][lm] = av.z; As[lkq*4+3][lm] = av.w;
    *(float4*)&Bs[lk][ln4*4] = bv;
    __syncthreads();
    #pragma unroll
    for (int kk = 0; kk < 16; ++kk){
      const float4 a = *(const float4*)&As[kk][ty*4];
      const float4 b = *(const float4*)&Bs[kk][tx*4];
      acc[0][0] += a.x*b.x; acc[0][1] += a.x*b.y; acc[0][2] += a.x*b.z; acc[0][3] += a.x*b.w;
      acc[1][0] += a.y*b.x; acc[1][1] += a.y*b.y; acc[1][2] += a.y*b.z; acc[1][3] += a.y*b.w;
      acc[2][0] += a.z*b.x; acc[2][1] += a.z*b.y; acc[2][2] += a.z*b.z; acc[2][3] += a.z*b.w;
      acc[3][0] += a.w*b.x; acc[3][1] += a.w*b.y; acc[3][2] += a.w*b.z; acc[3][3] += a.w*b.w;
    }
    __syncthreads();
  }

  float bv0 = 0.f, bv1 = 0.f, bv2 = 0.f, bv3 = 0.f;
  if (bias){
    const float4 b4 = *(const float4*)&bias[n0 + tx*4];
    bv0 = b4.x; bv1 = b4.y; bv2 = b4.z; bv3 = b4.w;
  }
  #pragma unroll
  for (int i = 0; i < 4; ++i){
    int r = m0 + ty*4 + i;
    if (r < M){
      float4 o;
      o.x = acc[i][0] + bv0; o.y = acc[i][1] + bv1; o.z = acc[i][2] + bv2; o.w = acc[i][3] + bv3;
      if (ACT == 1){ o.x = fmaxf(o.x,0.f); o.y = fmaxf(o.y,0.f); o.z = fmaxf(o.z,0.f); o.w = fmaxf(o.w,0.f); }
      *(float4*)&C[(size_t)r*N + n0 + tx*4] = o;
    }
  }
}

// ---------------- GCN aggregation + BN + ReLU ----------------
// 16 independent row-loads in flight per wave (2 halves x unroll 8).

__global__ __launch_bounds__(256) void agg_k(const _Float16* __restrict__ hws, _Float16* __restrict__ hout,
                                             const int* __restrict__ rowptr, const int* __restrict__ col,
                                             const float* __restrict__ dinv,
                                             const float* __restrict__ bgnn, const float* __restrict__ gamma,
                                             const float* __restrict__ beta, const float* __restrict__ mean,
                                             const float* __restrict__ var, int N){
  int n = (blockIdx.x * blockDim.x + threadIdx.x) >> 6;
  if (n >= N) return;
  int lane = threadIdx.x & 63;
  int half = lane >> 5;
  int sl   = lane & 31;
  int f    = sl * 4;
  int beg = rowptr[n], end = rowptr[n+1];
  const _Float16* hwsf = hws + f;

  half4_t H0 = {0,0,0,0}, H1 = {0,0,0,0}, H2 = {0,0,0,0}, H3 = {0,0,0,0};
  half4_t H4 = {0,0,0,0}, H5 = {0,0,0,0}, H6 = {0,0,0,0}, H7 = {0,0,0,0};

  int j = beg + half;
  for (; j + 14 < end; j += 16){
    int s0 = col[j],    s1 = col[j+2],  s2 = col[j+4],  s3 = col[j+6];
    int s4 = col[j+8],  s5 = col[j+10], s6 = col[j+12], s7 = col[j+14];
    H0 += *(const half4_t*)&hwsf[(size_t)s0*128];
    H1 += *(const half4_t*)&hwsf[(size_t)s1*128];
    H2 += *(const half4_t*)&hwsf[(size_t)s2*128];
    H3 += *(const half4_t*)&hwsf[(size_t)s3*128];
    H4 += *(const half4_t*)&hwsf[(size_t)s4*128];
    H5 += *(const half4_t*)&hwsf[(size_t)s5*128];
    H6 += *(const half4_t*)&hwsf[(size_t)s6*128];
    H7 += *(const half4_t*)&hwsf[(size_t)s7*128];
  }
  for (; j + 6 < end; j += 8){
    int s0 = col[j], s1 = col[j+2], s2 = col[j+4], s3 = col[j+6];
    H0 += *(const half4_t*)&hwsf[(size_t)s0*128];
    H1 += *(const half4_t*)&hwsf[(size_t)s1*128];
    H2 += *(const half4_t*)&hwsf[(size_t)s2*128];
    H3 += *(const half4_t*)&hwsf[(size_t)s3*128];
  }
  for (; j < end; j += 2){
    int s0 = col[j];
    H0 += *(const half4_t*)&hwsf[(size_t)s0*128];
  }

  float4 A0;
  A0.x = ((float)H0[0] + (float)H1[0]) + ((float)H2[0] + (float)H3[0])
       + ((float)H4[0] + (float)H5[0]) + ((float)H6[0] + (float)H7[0]);
  A0.y = ((float)H0[1] + (float)H1[1]) + ((float)H2[1] + (float)H3[1])
       + ((float)H4[1] + (float)H5[1]) + ((float)H6[1] + (float)H7[1]);
  A0.z = ((float)H0[2] + (float)H1[2]) + ((float)H2[2] + (float)H3[2])
       + ((float)H4[2] + (float)H5[2]) + ((float)H6[2] + (float)H7[2]);
  A0.w = ((float)H0[3] + (float)H1[3]) + ((float)H2[3] + (float)H3[3])
       + ((float)H4[3] + (float)H5[3]) + ((float)H6[3] + (float)H7[3]);

  A0.x += __shfl_xor(A0.x, 32, 64);
  A0.y += __shfl_xor(A0.y, 32, 64);
  A0.z += __shfl_xor(A0.z, 32, 64);
  A0.w += __shfl_xor(A0.w, 32, 64);

  if (half == 0){
    float di = dinv[n];
    const half4_t hv = *(const half4_t*)&hwsf[(size_t)n*128];
    const float4 bg = *(const float4*)&bgnn[f];
    const float4 gm = *(const float4*)&gamma[f];
    const float4 bt = *(const float4*)&beta[f];
    const float4 mn = *(const float4*)&mean[f];
    const float4 vr = *(const float4*)&var[f];
    float o0 = (di*(A0.x + (float)hv[0]) + bg.x - mn.x) * (gm.x * rsqrtf(vr.x + 1e-5f)) + bt.x;
    float o1 = (di*(A0.y + (float)hv[1]) + bg.y - mn.y) * (gm.y * rsqrtf(vr.y + 1e-5f)) + bt.y;
    float o2 = (di*(A0.z + (float)hv[2]) + bg.z - mn.z) * (gm.z * rsqrtf(vr.z + 1e-5f)) + bt.z;
    float o3 = (di*(A0.w + (float)hv[3]) + bg.w - mn.w) * (gm.w * rsqrtf(vr.w + 1e-5f)) + bt.w;
    half4_t o;
    o[0] = (_Float16)fmaxf(o0, 0.f);
    o[1] = (_Float16)fmaxf(o1, 0.f);
    o[2] = (_Float16)fmaxf(o2, 0.f);
    o[3] = (_Float16)fmaxf(o3, 0.f);
    *(half4_t*)&hout[(size_t)n*128 + f] = o;
  }
}

// ---------------- user gather, nlp bias, head ----------------

__global__ __launch_bounds__(256) void gather_k(const _Float16* __restrict__ h, const int* __restrict__ uidx,
                                                float* __restrict__ uh, int B){
  int g = blockIdx.x*256 + threadIdx.x;
  if (g >= B*128) return;
  int i = g >> 7, f = g & 127;
  uh[g] = (float)h[(size_t)uidx[i]*128 + f];
}

__global__ __launch_bounds__(256) void initc1_k(const float* __restrict__ b1, float* __restrict__ c1){
  c1[threadIdx.x] = b1[threadIdx.x];
}

// c1[c] += sum over 16-row chunk of nlp[d]*W1[(64+d)*256+c]; grid ceil(NLP/16), coalesced
__global__ __launch_bounds__(256) void c1acc_k(const float* __restrict__ nlp, const float* __restrict__ W1,
                                               float* __restrict__ c1, int NLP){
  int c = threadIdx.x;
  int d0 = blockIdx.x * 16;
  int d1 = d0 + 16 < NLP ? d0 + 16 : NLP;
  float acc = 0.f;
  for (int d = d0; d < d1; ++d)
    acc += nlp[d] * W1[(size_t)(64 + d) * 256 + c];
  atomicAdd(&c1[c], acc);
}

__global__ __launch_bounds__(256) void head_k(const float* __restrict__ z2, const float* __restrict__ W3,
                                              const float* __restrict__ b3, float* __restrict__ out, int B){
  int gid = blockIdx.x * blockDim.x + threadIdx.x;
  int u = gid >> 6, l = gid & 63;
  if (u >= B) return;
  float v = z2[(size_t)u*128 + l] * W3[l] + z2[(size_t)u*128 + 64 + l] * W3[64 + l];
  #pragma unroll
  for (int off = 32; off; off >>= 1) v += __shfl_down(v, off, 64);
  if (l == 0) out[u] = 1.f / (1.f + expf(-(v + b3[0])));
}

// ---------------- host ----------------

static void launch_gemm(int act, const float* A, const float* Bm, const float* bias, float* C,
                        int M, int N, int K, hipStream_t s){
  dim3 g((M + 63) / 64, N / 64);
  if (act) hipLaunchKernelGGL((gemm_k<1>), g, dim3(256), 0, s, A, Bm, bias, C, M, N, K);
  else     hipLaunchKernelGGL((gemm_k<0>), g, dim3(256), 0, s, A, Bm, bias, C, M, N, K);
}

extern "C" void kernel_launch(void* const* d_in, const int* in_sizes, int n_in,
                              void* d_out, int out_size, void* d_ws, size_t ws_size,
                              hipStream_t stream){
  const float* x     = (const float*)d_in[0];
  const float* nlp   = (const float*)d_in[1];
  const int*   eidx  = (const int*)  d_in[2];
  const int*   uidx  = (const int*)  d_in[3];
  const float* W_in  = (const float*)d_in[4];
  const float* b_in  = (const float*)d_in[5];
  const float* W_gnn = (const float*)d_in[6];
  const float* b_gnn = (const float*)d_in[7];
  const float* gam   = (const float*)d_in[8];
  const float* bet   = (const float*)d_in[9];
  const float* mean  = (const float*)d_in[10];
  const float* var   = (const float*)d_in[11];
  const float* Wproj = (const float*)d_in[12];
  const float* bproj = (const float*)d_in[13];
  const float* W1    = (const float*)d_in[14];
  const float* b1    = (const float*)d_in[15];
  const float* W2    = (const float*)d_in[16];
  const float* b2    = (const float*)d_in[17];
  const float* W3    = (const float*)d_in[18];
  const float* b3    = (const float*)d_in[19];
  float* out = (float*)d_out;

  const int N   = in_sizes[0] / 128;   // 100000
  const int E   = in_sizes[2] / 2;     // 1600000
  const int B   = in_sizes[3];         // 4096
  const int NLP = in_sizes[1];         // 786
  const int HID = 128;

  char* p = (char*)d_ws;
  auto carve = [&](size_t bytes) -> void* {
    void* q = (void*)p;
    p += (bytes + 255) & ~(size_t)255;
    return q;
  };
  int*            cnt    = (int*)           carve((size_t)N * 4);
  int*            rowptr = (int*)           carve((size_t)(N + 1) * 4);
  unsigned short* rank   = (unsigned short*)carve((size_t)E * 2);
  int*            bsum   = (int*)           carve(512 * 4);
  int*            boff   = (int*)           carve(512 * 4);
  float*          dinv   = (float*)         carve((size_t)N * 4);
  int*            col    = (int*)           carve((size_t)E * 4);
  _Float16*       Bt     = (_Float16*)      carve((size_t)4 * 128 * 128 * 2);
  _Float16*       h      = (_Float16*)      carve((size_t)N * HID * 2);
  _Float16*       hws    = (_Float16*)      carve((size_t)N * HID * 2);
  float*          uh     = (float*)         carve((size_t)B * HID * 4);
  float*          embu   = (float*)         carve((size_t)B * 64 * 4);
  float*          z1     = (float*)         carve((size_t)B * 256 * 4);
  float*          z2     = (float*)         carve((size_t)B * 128 * 4);
  float*          c1     = (float*)         carve(256 * 4);

  const int* src = eidx;
  const int* dst = eidx + E;

  const int NB = (N + 255) / 256;   // 391 (<512)
  const int GB = (N + 127) / 128;   // 782 gemm blocks

  // ---- CSR build ----
  hipMemsetAsync(cnt, 0, (size_t)N * 4, stream);
  hipLaunchKernelGGL(hist_k, dim3((E + 255) / 256), dim3(256), 0, stream, dst, cnt, rank, E);
  hipLaunchKernelGGL(blocksum_k, dim3(NB), dim3(256), 0, stream, cnt, bsum, N);
  hipLaunchKernelGGL(scan_small_k, dim3(1), dim3(512), 0, stream, bsum, boff, NB);
  hipLaunchKernelGGL(scan_final_k, dim3(NB), dim3(256), 0, stream, cnt, boff, rowptr, dinv, N);
  hipLaunchKernelGGL(fill_k, dim3((E/2 + 255) / 256), dim3(256), 0, stream, src, dst, rowptr, rank, col, E);

  // ---- weight prep (fp16, transposed) ----
  hipLaunchKernelGGL(prepw_k, dim3(256), dim3(256), 0, stream, W_in, W_gnn, Bt);

  // ---- input projection: h = (fp16) relu(x @ W_in + b_in)  [MFMA] ----
  hipLaunchKernelGGL((mgemm_k<0,0>), dim3(GB), dim3(256), 0, stream,
                     (const void*)x, Bt, b_in, (const float*)nullptr, h, N);

  // ---- 3 GCN layers ----
  for (int i = 0; i < 3; ++i){
    hipLaunchKernelGGL((mgemm_k<1,1>), dim3(GB), dim3(256), 0, stream,
                       (const void*)h, Bt + (size_t)(i+1)*16384, (const float*)nullptr, dinv, hws, N);
    hipLaunchKernelGGL(agg_k, dim3((N * 64 + 255) / 256), dim3(256), 0, stream,
                       hws, h, rowptr, col, dinv,
                       b_gnn + i * 128, gam + i * 128, bet + i * 128, mean + i * 128, var + i * 128, N);
  }

  // ---- user head ----
  hipLaunchKernelGGL(gather_k, dim3((B * 128 + 255) / 256), dim3(256), 0, stream, h, uidx, uh, B);
  hipLaunchKernelGGL(initc1_k, dim3(1), dim3(256), 0, stream, b1, c1);
  hipLaunchKernelGGL(c1acc_k, dim3((NLP + 15) / 16), dim3(256), 0, stream, nlp, W1, c1, NLP);

  launch_gemm(0, uh, Wproj, bproj, embu, B, 64, 128, stream);
  launch_gemm(1, embu, W1, c1, z1, B, 256, 64, stream);
  launch_gemm(1, z1, W2, b2, z2, B, 128, 256, stream);
  hipLaunchKernelGGL(head_k, dim3((B * 64 + 255) / 256), dim3(256), 0, stream, z2, W3, b3, out, B);
}